// Round 12
// baseline (1818.346 us; speedup 1.0000x reference)
//
#include <hip/hip_runtime.h>
#include <hip/hip_bf16.h>

#define DI __device__ __forceinline__

typedef __bf16 bf16_t;
typedef __bf16 bf16x8 __attribute__((ext_vector_type(8)));
typedef float f32x4 __attribute__((ext_vector_type(4)));

static constexpr int Bc = 4, Tc = 1024, Cc = 768, Hc = 12, Lc = 6, Vc = 50257;
static constexpr int FFc = 3072, BT = Bc * Tc;  // 4096
static constexpr int Vpad = 50304;              // 393 * 128
static constexpr int NPAN = Vpad / 128;         // 393 head panels

DI void gld_lds16(const void* g, void* l) {
  __builtin_amdgcn_global_load_lds((__attribute__((address_space(1))) void*)(void*)g,
                                   (__attribute__((address_space(3))) void*)l, 16, 0, 0);
}
DI bf16_t f2b(float v) { return (bf16_t)v; }
DI unsigned short b2u(bf16_t h) { union { bf16_t b; unsigned short u; } x; x.b = h; return x.u; }

// ---------------- weight transpose + f32->bf16 convert: src[K][N] -> dst[Npad][K]
__global__ void tconv(const float* __restrict__ src, bf16_t* __restrict__ dst,
                      const int K, const int N, const long sStride, const long dStride) {
  __shared__ float t[32][33];
  src += (long)blockIdx.z * sStride;
  dst += (long)blockIdx.z * dStride;
  const int n0 = blockIdx.x * 32, k0 = blockIdx.y * 32;
  const int tr = threadIdx.x >> 5, tc = threadIdx.x & 31;
#pragma unroll
  for (int i = 0; i < 4; ++i) {
    const int n = n0 + tc;
    t[tr + i * 8][tc] = (n < N) ? src[(long)(k0 + tr + i * 8) * N + n] : 0.f;
  }
  __syncthreads();
#pragma unroll
  for (int i = 0; i < 4; ++i)
    dst[(long)(n0 + tr + i * 8) * K + k0 + tc] = f2b(t[tc][tr + i * 8]);
}

// ---------------- fused embedding + LN1(layer 0): one wave per row, 4 rows/block
__global__ void embed_ln(const int* __restrict__ idx, const float* __restrict__ tok,
                         const float* __restrict__ pos, const float* __restrict__ g,
                         const float* __restrict__ b, float* __restrict__ X,
                         bf16_t* __restrict__ out) {
  const int lane = threadIdx.x & 63;
  const long row = (long)blockIdx.x * 4 + (threadIdx.x >> 6);
  const int t = (int)(row & (Tc - 1));
  const float* tr = tok + (long)idx[row] * Cc;
  const float* pr = pos + (long)t * Cc;
  float v[12];
  float s = 0.f;
#pragma unroll
  for (int i = 0; i < 3; ++i) {
    const int c = lane * 4 + i * 256;
    const float4 a = *(const float4*)(tr + c);
    const float4 p = *(const float4*)(pr + c);
    float4 x;
    x.x = a.x + p.x; x.y = a.y + p.y; x.z = a.z + p.z; x.w = a.w + p.w;
    *(float4*)(X + row * Cc + c) = x;
    v[i * 4 + 0] = x.x; v[i * 4 + 1] = x.y; v[i * 4 + 2] = x.z; v[i * 4 + 3] = x.w;
    s += x.x + x.y + x.z + x.w;
  }
#pragma unroll
  for (int o = 1; o < 64; o <<= 1) s += __shfl_xor(s, o);
  const float mean = s * (1.f / 768.f);
  float q = 0.f;
#pragma unroll
  for (int j = 0; j < 12; ++j) { const float d = v[j] - mean; q += d * d; }
#pragma unroll
  for (int o = 1; o < 64; o <<= 1) q += __shfl_xor(q, o);
  const float rstd = rsqrtf(q * (1.f / 768.f) + 1e-5f);
#pragma unroll
  for (int i = 0; i < 3; ++i) {
    const int c = lane * 4 + i * 256;
    const float4 gg = *(const float4*)(g + c);
    const float4 bb = *(const float4*)(b + c);
    ushort4 o4;
    o4.x = b2u(f2b((v[i * 4 + 0] - mean) * rstd * gg.x + bb.x));
    o4.y = b2u(f2b((v[i * 4 + 1] - mean) * rstd * gg.y + bb.y));
    o4.z = b2u(f2b((v[i * 4 + 2] - mean) * rstd * gg.z + bb.z));
    o4.w = b2u(f2b((v[i * 4 + 3] - mean) * rstd * gg.w + bb.w));
    *(ushort4*)(out + row * Cc + c) = o4;
  }
}

// ---------------- fused split-K reduce + residual + LN: X += P0+P1+bias; out = LN(X)
__global__ void red_ln(const float* __restrict__ P, const float* __restrict__ bias,
                       const float* __restrict__ g, const float* __restrict__ b,
                       float* __restrict__ X, bf16_t* __restrict__ out) {
  const int lane = threadIdx.x & 63;
  const long row = (long)blockIdx.x * 4 + (threadIdx.x >> 6);
  float v[12];
  float s = 0.f;
#pragma unroll
  for (int i = 0; i < 3; ++i) {
    const int c = lane * 4 + i * 256;
    const float4 x0 = *(const float4*)(X + row * Cc + c);
    const float4 p0 = *(const float4*)(P + row * Cc + c);
    const float4 p1 = *(const float4*)(P + (size_t)BT * Cc + row * Cc + c);
    const float4 bb = *(const float4*)(bias + c);
    float4 x;
    x.x = x0.x + p0.x + p1.x + bb.x;
    x.y = x0.y + p0.y + p1.y + bb.y;
    x.z = x0.z + p0.z + p1.z + bb.z;
    x.w = x0.w + p0.w + p1.w + bb.w;
    *(float4*)(X + row * Cc + c) = x;
    v[i * 4 + 0] = x.x; v[i * 4 + 1] = x.y; v[i * 4 + 2] = x.z; v[i * 4 + 3] = x.w;
    s += x.x + x.y + x.z + x.w;
  }
#pragma unroll
  for (int o = 1; o < 64; o <<= 1) s += __shfl_xor(s, o);
  const float mean = s * (1.f / 768.f);
  float q = 0.f;
#pragma unroll
  for (int j = 0; j < 12; ++j) { const float d = v[j] - mean; q += d * d; }
#pragma unroll
  for (int o = 1; o < 64; o <<= 1) q += __shfl_xor(q, o);
  const float rstd = rsqrtf(q * (1.f / 768.f) + 1e-5f);
#pragma unroll
  for (int i = 0; i < 3; ++i) {
    const int c = lane * 4 + i * 256;
    const float4 gg = *(const float4*)(g + c);
    const float4 bb = *(const float4*)(b + c);
    ushort4 o4;
    o4.x = b2u(f2b((v[i * 4 + 0] - mean) * rstd * gg.x + bb.x));
    o4.y = b2u(f2b((v[i * 4 + 1] - mean) * rstd * gg.y + bb.y));
    o4.z = b2u(f2b((v[i * 4 + 2] - mean) * rstd * gg.z + bb.z));
    o4.w = b2u(f2b((v[i * 4 + 3] - mean) * rstd * gg.w + bb.w));
    *(ushort4*)(out + row * Cc + c) = o4;
  }
}

// ---------------- 128x128 GEMM, m97 structure.
// EPI: 0 = bf16 out; 1 = bf16 relu(v+bias); 4 = split-K f32 partial (blockIdx.z);
//      5 = QKV: Q,K cols -> bf16 out; V cols (n0>=1536) -> transposed bf16 to vtr
template <int EPI>
__launch_bounds__(256, 4)
__global__ void gemm_bt(const bf16_t* __restrict__ A, const bf16_t* __restrict__ Bt,
                        const float* __restrict__ bias, bf16_t* __restrict__ outB,
                        bf16_t* __restrict__ vtr, float* __restrict__ fpart,
                        const int N, const int K, const int ldk, const int ldo) {
  __shared__ __align__(16) bf16_t As[128 * 64];
  __shared__ __align__(16) bf16_t Bs[128 * 64];
  const int tid = threadIdx.x;
  const int lane = tid & 63, wid = tid >> 6;
  const int l4 = lane >> 4, l15 = lane & 15;
  const int wr = wid >> 1, wc = wid & 1;

  int flat;
  {
    const int nwg = gridDim.x * gridDim.y;
    int f = (int)blockIdx.y * gridDim.x + (int)blockIdx.x;
    const int q = nwg >> 3, r = nwg & 7;
    const int xcd = f & 7, pos = f >> 3;
    flat = (xcd < r) ? xcd * (q + 1) + pos : r * (q + 1) + (xcd - r) * q + pos;
  }
  const long m0 = (long)(flat / gridDim.x) * 128;
  const long n0 = (long)(flat % gridDim.x) * 128;
  const long koff = (long)blockIdx.z * K;

  const bf16_t* Ag = A + m0 * ldk + koff;
  const bf16_t* Bg = Bt + n0 * ldk + koff;
  const int srow = tid >> 3, scol = tid & 7;

  f32x4 acc[4][4];
#pragma unroll
  for (int m = 0; m < 4; ++m)
#pragma unroll
    for (int n = 0; n < 4; ++n) acc[m][n] = (f32x4){0.f, 0.f, 0.f, 0.f};

  const int nkt = K >> 6;
  for (int kt = 0; kt < nkt; ++kt) {
    const int kb = kt << 6;
#pragma unroll
    for (int i = 0; i < 4; ++i) {
      const int r_ = i * 32 + srow;
      const int c8 = scol ^ (r_ & 7);
      gld_lds16(Ag + (long)r_ * ldk + kb + c8 * 8, As + (i * 256 + tid) * 8);
      gld_lds16(Bg + (long)r_ * ldk + kb + c8 * 8, Bs + (i * 256 + tid) * 8);
    }
    __syncthreads();
#pragma unroll
    for (int kk = 0; kk < 2; ++kk) {
      bf16x8 af[4], bfv[4];
#pragma unroll
      for (int m = 0; m < 4; ++m) {
        const int row = wr * 64 + m * 16 + l15;
        af[m] = *(const bf16x8*)((const char*)As +
                 ((row * 128 + kk * 64 + l4 * 16) ^ ((row & 7) << 4)));
      }
#pragma unroll
      for (int n = 0; n < 4; ++n) {
        const int row = wc * 64 + n * 16 + l15;
        bfv[n] = *(const bf16x8*)((const char*)Bs +
                 ((row * 128 + kk * 64 + l4 * 16) ^ ((row & 7) << 4)));
      }
#pragma unroll
      for (int m = 0; m < 4; ++m)
#pragma unroll
        for (int n = 0; n < 4; ++n)
          acc[m][n] = __builtin_amdgcn_mfma_f32_16x16x32_bf16(af[m], bfv[n], acc[m][n], 0, 0, 0);
    }
    __syncthreads();
  }

  if constexpr (EPI == 5) {
    if ((int)n0 >= 1536) {
      // V region: write ONLY transposed VT[(col-1536)][row], 8B per (m,n)
#pragma unroll
      for (int m = 0; m < 4; ++m) {
        const long rowb = m0 + wr * 64 + m * 16 + l4 * 4;
#pragma unroll
        for (int n = 0; n < 4; ++n) {
          const int col = (int)n0 + wc * 64 + n * 16 + l15;
          ushort4 w;
          w.x = b2u(f2b(acc[m][n][0]));
          w.y = b2u(f2b(acc[m][n][1]));
          w.z = b2u(f2b(acc[m][n][2]));
          w.w = b2u(f2b(acc[m][n][3]));
          *(ushort4*)(vtr + (size_t)(col - 1536) * BT + rowb) = w;
        }
      }
      return;
    }
  }
#pragma unroll
  for (int m = 0; m < 4; ++m) {
    const long rowb = m0 + wr * 64 + m * 16 + l4 * 4;
#pragma unroll
    for (int n = 0; n < 4; ++n) {
      const int col = (int)n0 + wc * 64 + n * 16 + l15;
#pragma unroll
      for (int r = 0; r < 4; ++r) {
        const float v = acc[m][n][r];
        const long row = rowb + r;
        if constexpr (EPI == 0 || EPI == 5) {
          outB[row * ldo + col] = f2b(v);
        } else if constexpr (EPI == 1) {
          const float z = v + bias[col];
          outB[row * ldo + col] = f2b(z > 0.f ? z : 0.f);
        } else {
          fpart[((size_t)blockIdx.z * BT + row) * ldo + col] = v;
        }
      }
    }
  }
}

// ---------------- HEAD: 128^2, n-fastest, occ-4. No-max partials, no shuffles.
// Logit stores NON-TEMPORAL (read-once output): keeps 77MB weight stream resident
// in L3 across the 32 m-tile passes instead of being evicted by 824MB of writes.
__launch_bounds__(256, 4)
__global__ void head_k(const bf16_t* __restrict__ A, const bf16_t* __restrict__ Bt,
                       const float* __restrict__ bias, float* __restrict__ outF,
                       const int K, const int ldo, float* __restrict__ part1) {
  __shared__ __align__(16) bf16_t As[128 * 64];
  __shared__ __align__(16) bf16_t Bs[128 * 64];
  const int tid = threadIdx.x;
  const int lane = tid & 63, wid = tid >> 6;
  const int l4 = lane >> 4, l15 = lane & 15;
  const int wr = wid >> 1, wc = wid & 1;
  const long m0 = (long)blockIdx.y * 128;
  const long n0 = (long)blockIdx.x * 128;

  const bf16_t* Ag = A + m0 * K;
  const bf16_t* Bg = Bt + n0 * K;
  const int srow = tid >> 3, scol = tid & 7;

  f32x4 acc[4][4];
#pragma unroll
  for (int m = 0; m < 4; ++m)
#pragma unroll
    for (int n = 0; n < 4; ++n) acc[m][n] = (f32x4){0.f, 0.f, 0.f, 0.f};

  const int nkt = K >> 6;
  for (int kt = 0; kt < nkt; ++kt) {
    const int kb = kt << 6;
#pragma unroll
    for (int i = 0; i < 4; ++i) {
      const int r_ = i * 32 + srow;
      const int c8 = scol ^ (r_ & 7);
      gld_lds16(Ag + (long)r_ * K + kb + c8 * 8, As + (i * 256 + tid) * 8);
      gld_lds16(Bg + (long)r_ * K + kb + c8 * 8, Bs + (i * 256 + tid) * 8);
    }
    __syncthreads();
#pragma unroll
    for (int kk = 0; kk < 2; ++kk) {
      bf16x8 af[4], bfv[4];
#pragma unroll
      for (int m = 0; m < 4; ++m) {
        const int row = wr * 64 + m * 16 + l15;
        af[m] = *(const bf16x8*)((const char*)As +
                 ((row * 128 + kk * 64 + l4 * 16) ^ ((row & 7) << 4)));
      }
#pragma unroll
      for (int n = 0; n < 4; ++n) {
        const int row = wc * 64 + n * 16 + l15;
        bfv[n] = *(const bf16x8*)((const char*)Bs +
                 ((row * 128 + kk * 64 + l4 * 16) ^ ((row & 7) << 4)));
      }
#pragma unroll
      for (int m = 0; m < 4; ++m)
#pragma unroll
        for (int n = 0; n < 4; ++n)
          acc[m][n] = __builtin_amdgcn_mfma_f32_16x16x32_bf16(af[m], bfv[n], acc[m][n], 0, 0, 0);
    }
    __syncthreads();
  }

  const bool full = ((int)n0 + 128) <= Vc;  // 392/393 panels: no col guard needed

  // ---- thread-local exp-sums -> LDS transpose (no shuffles)
  float* ps = (float*)&As[0];  // [128][33]
#pragma unroll
  for (int m = 0; m < 4; ++m)
#pragma unroll
    for (int r = 0; r < 4; ++r) {
      float s = 0.f;
      if (full) {
#pragma unroll
        for (int n = 0; n < 4; ++n) {
          const int col = (int)n0 + wc * 64 + n * 16 + l15;
          s += __expf(acc[m][n][r] + bias[col]);
        }
      } else {
#pragma unroll
        for (int n = 0; n < 4; ++n) {
          const int col = (int)n0 + wc * 64 + n * 16 + l15;
          s += (col < Vc) ? __expf(acc[m][n][r] + bias[col]) : 0.f;
        }
      }
      ps[(wr * 64 + m * 16 + l4 * 4 + r) * 33 + wc * 16 + l15] = s;
    }
  __syncthreads();
  if (tid < 128) {
    float S = 0.f;
#pragma unroll
    for (int j = 0; j < 32; ++j) S += ps[tid * 33 + j];
    part1[(m0 + tid) * NPAN + (int)(n0 >> 7)] = S;
  }

  // ---- logit stores last, non-temporal
  if (full) {
#pragma unroll
    for (int m = 0; m < 4; ++m) {
      const long rowb = m0 + wr * 64 + m * 16 + l4 * 4;
#pragma unroll
      for (int n = 0; n < 4; ++n) {
        const int col = (int)n0 + wc * 64 + n * 16 + l15;
#pragma unroll
        for (int r = 0; r < 4; ++r)
          __builtin_nontemporal_store(acc[m][n][r] + bias[col],
                                      &outF[(rowb + r) * (long)ldo + col]);
      }
    }
  } else {
#pragma unroll
    for (int m = 0; m < 4; ++m) {
      const long rowb = m0 + wr * 64 + m * 16 + l4 * 4;
#pragma unroll
      for (int n = 0; n < 4; ++n) {
        const int col = (int)n0 + wc * 64 + n * 16 + l15;
#pragma unroll
        for (int r = 0; r < 4; ++r)
          if (col < Vc)
            __builtin_nontemporal_store(acc[m][n][r] + bias[col],
                                        &outF[(rowb + r) * (long)ldo + col]);
      }
    }
  }
}

// ---------------- causal flash attention: V^T pre-transposed globally (VT), staged
// like K via gld_lds16. 3 blocks/CU = whole grid co-resident.
__launch_bounds__(256, 3)
__global__ void attn_k(const bf16_t* __restrict__ qkv, const bf16_t* __restrict__ vt,
                       bf16_t* __restrict__ att) {
  const int qt = blockIdx.x;
  const int bh = blockIdx.y;
  const int b = bh / Hc, h = bh % Hc;
  const int tid = threadIdx.x;
  const int lane = tid & 63, wid = tid >> 6;
  const int l4 = lane >> 4, l15 = lane & 15;

  __shared__ __align__(16) bf16_t Ks[64 * 64];    // swizzled [kv][64]
  __shared__ __align__(16) bf16_t Vts[64 * 64];   // swizzled [d][kv]
  __shared__ __align__(16) bf16_t Ps[4][16 * 64]; // per-wave swizzled P

  const long qrow0 = (long)b * Tc + qt * 64 + wid * 16;
  bf16x8 qf0, qf1;
  {
    const bf16_t* qp = qkv + (qrow0 + l15) * 2304 + h * 64 + l4 * 8;
    qf0 = *(const bf16x8*)qp;
    qf1 = *(const bf16x8*)(qp + 32);
  }
  f32x4 oacc[4];
#pragma unroll
  for (int f = 0; f < 4; ++f) oacc[f] = (f32x4){0.f, 0.f, 0.f, 0.f};
  float mrow[4] = {-3.0e38f, -3.0e38f, -3.0e38f, -3.0e38f};
  float lrw[4] = {0.f, 0.f, 0.f, 0.f};

  for (int kt = 0; kt <= qt; ++kt) {
    const long kvb = (long)b * Tc + kt * 64;
#pragma unroll
    for (int i = 0; i < 2; ++i) {  // K tile
      const int c = i * 256 + tid;
      const int r_ = c >> 3;
      const int c8 = (c & 7) ^ (r_ & 7);
      gld_lds16(qkv + (kvb + r_) * 2304 + Cc + h * 64 + c8 * 8, Ks + (size_t)c * 8);
    }
#pragma unroll
    for (int i = 0; i < 2; ++i) {  // V^T tile from global VT
      const int c = i * 256 + tid;
      const int r_ = c >> 3;
      const int c8 = (c & 7) ^ (r_ & 7);
      gld_lds16(vt + (size_t)(h * 64 + r_) * BT + kvb + c8 * 8, Vts + (size_t)c * 8);
    }
    __syncthreads();

    f32x4 sf[4];
#pragma unroll
    for (int f = 0; f < 4; ++f) {
      const int row = f * 16 + l15;
      const bf16x8 kb0 = *(const bf16x8*)((const char*)Ks +
                        ((row * 128 + l4 * 16) ^ ((row & 7) << 4)));
      const bf16x8 kb1 = *(const bf16x8*)((const char*)Ks +
                        ((row * 128 + 64 + l4 * 16) ^ ((row & 7) << 4)));
      f32x4 z = (f32x4){0.f, 0.f, 0.f, 0.f};
      z = __builtin_amdgcn_mfma_f32_16x16x32_bf16(qf0, kb0, z, 0, 0, 0);
      sf[f] = __builtin_amdgcn_mfma_f32_16x16x32_bf16(qf1, kb1, z, 0, 0, 0);
    }
    float alpha[4];
#pragma unroll
    for (int r = 0; r < 4; ++r) {
      const int qpos = qt * 64 + wid * 16 + l4 * 4 + r;
      float mx = -3.0e38f;
#pragma unroll
      for (int f = 0; f < 4; ++f) {
        const int kpos = kt * 64 + f * 16 + l15;
        float sv = sf[f][r] * 0.125f;
        sv = (kpos <= qpos) ? sv : -1e9f;
        sf[f][r] = sv;
        mx = fmaxf(mx, sv);
      }
      mx = fmaxf(mx, __shfl_xor(mx, 1));
      mx = fmaxf(mx, __shfl_xor(mx, 2));
      mx = fmaxf(mx, __shfl_xor(mx, 4));
      mx = fmaxf(mx, __shfl_xor(mx, 8));
      const float mn = fmaxf(mrow[r], mx);
      alpha[r] = __expf(mrow[r] - mn);
      mrow[r] = mn;
      float rs = 0.f;
#pragma unroll
      for (int f = 0; f < 4; ++f) {
        const float pw = __expf(sf[f][r] - mn);
        sf[f][r] = pw;
        rs += pw;
      }
      rs += __shfl_xor(rs, 1); rs += __shfl_xor(rs, 2);
      rs += __shfl_xor(rs, 4); rs += __shfl_xor(rs, 8);
      lrw[r] = lrw[r] * alpha[r] + rs;
    }
    char* pb = (char*)&Ps[wid][0];
#pragma unroll
    for (int r = 0; r < 4; ++r) {
      const int i_ = l4 * 4 + r;
#pragma unroll
      for (int f = 0; f < 4; ++f) {
        const int j_ = f * 16 + l15;
        *(bf16_t*)(pb + ((i_ * 128 + j_ * 2) ^ ((i_ & 7) << 4))) = f2b(sf[f][r]);
      }
    }
#pragma unroll
    for (int f = 0; f < 4; ++f)
#pragma unroll
      for (int r = 0; r < 4; ++r) oacc[f][r] *= alpha[r];

    bf16x8 pa0, pa1;
    {
      const int row = l15;
      pa0 = *(const bf16x8*)(pb + ((row * 128 + l4 * 16) ^ ((row & 7) << 4)));
      pa1 = *(const bf16x8*)(pb + ((row * 128 + 64 + l4 * 16) ^ ((row & 7) << 4)));
    }
#pragma unroll
    for (int f = 0; f < 4; ++f) {
      const int row = f * 16 + l15;
      const bf16x8 vb0 = *(const bf16x8*)((const char*)Vts +
                        ((row * 128 + l4 * 16) ^ ((row & 7) << 4)));
      const bf16x8 vb1 = *(const bf16x8*)((const char*)Vts +
                        ((row * 128 + 64 + l4 * 16) ^ ((row & 7) << 4)));
      oacc[f] = __builtin_amdgcn_mfma_f32_16x16x32_bf16(pa0, vb0, oacc[f], 0, 0, 0);
      oacc[f] = __builtin_amdgcn_mfma_f32_16x16x32_bf16(pa1, vb1, oacc[f], 0, 0, 0);
    }
    __syncthreads();
  }
#pragma unroll
  for (int f = 0; f < 4; ++f) {
    const int col = h * 64 + f * 16 + l15;
#pragma unroll
    for (int r = 0; r < 4; ++r) {
      const long row = qrow0 + l4 * 4 + r;
      att[row * Cc + col] = f2b(oacc[f][r] / lrw[r]);
    }
  }
}

// ---------------- loss
__global__ void loss_rows(const float* __restrict__ p1, const float* __restrict__ logits,
                          const int* __restrict__ tgt, float* __restrict__ part) {
  const int row = blockIdx.x * 4 + (threadIdx.x >> 6);
  const int lane = threadIdx.x & 63;
  float S = 0.f;
  for (int i = lane; i < NPAN; i += 64) S += p1[(long)row * NPAN + i];
#pragma unroll
  for (int o = 1; o < 64; o <<= 1) S += __shfl_xor(S, o);
  if (lane == 0)
    part[row] = logf(S) - logits[(long)row * Vc + tgt[row]];
}

__global__ void loss_final(const float* __restrict__ part, float* __restrict__ out) {
  float s = 0.f;
  for (int i = threadIdx.x; i < BT; i += 256) s += part[i];
#pragma unroll
  for (int o = 1; o < 64; o <<= 1) s += __shfl_xor(s, o);
  __shared__ float sw[4];
  const int wid = threadIdx.x >> 6;
  if ((threadIdx.x & 63) == 0) sw[wid] = s;
  __syncthreads();
  if (threadIdx.x == 0) out[0] = (sw[0] + sw[1] + sw[2] + sw[3]) / (float)BT;
}

extern "C" void kernel_launch(void* const* d_in, const int* in_sizes, int n_in,
                              void* d_out, int out_size, void* d_ws, size_t ws_size,
                              hipStream_t stream) {
  (void)in_sizes; (void)n_in; (void)out_size; (void)ws_size;
  const int* idx = (const int*)d_in[0];
  const int* tgt = (const int*)d_in[1];
  const float* tok = (const float*)d_in[2];
  const float* pos = (const float*)d_in[3];
  const float* Wq = (const float*)d_in[4];
  const float* Wk = (const float*)d_in[5];
  const float* Wv = (const float*)d_in[6];
  const float* Wp = (const float*)d_in[7];
  const float* bp = (const float*)d_in[8];
  const float* ln1g = (const float*)d_in[9];
  const float* ln1b = (const float*)d_in[10];
  const float* ln2g = (const float*)d_in[11];
  const float* ln2b = (const float*)d_in[12];
  const float* W1 = (const float*)d_in[13];
  const float* b1 = (const float*)d_in[14];
  const float* W2 = (const float*)d_in[15];
  const float* b2 = (const float*)d_in[16];
  const float* lnfg = (const float*)d_in[17];
  const float* lnfb = (const float*)d_in[18];
  const float* Wh = (const float*)d_in[19];
  const float* bh = (const float*)d_in[20];

  char* p = (char*)d_ws;
  auto take = [&](size_t bytes) { char* r = p; p += (bytes + 255) & ~(size_t)255; return r; };
  bf16_t* WTQKV = (bf16_t*)take((size_t)Lc * 2304 * Cc * 2);
  bf16_t* WTP   = (bf16_t*)take((size_t)Lc * Cc * Cc * 2);
  bf16_t* WT1   = (bf16_t*)take((size_t)Lc * FFc * Cc * 2);
  bf16_t* WT2   = (bf16_t*)take((size_t)Lc * Cc * FFc * 2);
  bf16_t* WTH   = (bf16_t*)take((size_t)Vpad * Cc * 2);
  float*  X     = (float*)take((size_t)BT * Cc * 4);
  bf16_t* Hb    = (bf16_t*)take((size_t)BT * Cc * 2);
  bf16_t* QKVb  = (bf16_t*)take((size_t)BT * 2304 * 2);
  bf16_t* ATT   = (bf16_t*)take((size_t)BT * Cc * 2);
  bf16_t* FFb   = (bf16_t*)take((size_t)BT * FFc * 2);
  bf16_t* VT    = (bf16_t*)take((size_t)BT * Cc * 2);      // V transposed [768][BT]
  float*  FPROJ = (float*)take((size_t)2 * BT * Cc * 4);   // proj split-K partials
  float*  FPART = (float*)QKVb;   // FF2 partials: QKVb+ATT dead during FF2
  float*  PART1 = (float*)FFb;    // head exp-sums (FFb dead after last FF2)
  float*  PART  = (float*)ATT;    // 16 KB row losses

  tconv<<<dim3(24, 24, Lc), 256, 0, stream>>>(Wq, WTQKV, Cc, Cc, (long)Cc * Cc, (long)2304 * Cc);
  tconv<<<dim3(24, 24, Lc), 256, 0, stream>>>(Wk, WTQKV + (size_t)Cc * Cc, Cc, Cc, (long)Cc * Cc, (long)2304 * Cc);
  tconv<<<dim3(24, 24, Lc), 256, 0, stream>>>(Wv, WTQKV + (size_t)2 * Cc * Cc, Cc, Cc, (long)Cc * Cc, (long)2304 * Cc);
  tconv<<<dim3(24, 24, Lc), 256, 0, stream>>>(Wp, WTP, Cc, Cc, (long)Cc * Cc, (long)Cc * Cc);
  tconv<<<dim3(96, 24, Lc), 256, 0, stream>>>(W1, WT1, Cc, FFc, (long)Cc * FFc, (long)FFc * Cc);
  tconv<<<dim3(24, 96, Lc), 256, 0, stream>>>(W2, WT2, FFc, Cc, (long)FFc * Cc, (long)Cc * FFc);
  tconv<<<dim3(Vpad / 32, 24, 1), 256, 0, stream>>>(Wh, WTH, Cc, Vc, 0, 0);

  embed_ln<<<BT / 4, 256, 0, stream>>>(idx, tok, pos, ln1g, ln1b, X, Hb);

  for (int l = 0; l < Lc; ++l) {
    const bf16_t* wqkv = WTQKV + (size_t)l * 2304 * Cc;
    const bf16_t* wp   = WTP + (size_t)l * Cc * Cc;
    const bf16_t* w1   = WT1 + (size_t)l * FFc * Cc;
    const bf16_t* w2   = WT2 + (size_t)l * Cc * FFc;
    gemm_bt<5><<<dim3(18, 32), 256, 0, stream>>>(Hb, wqkv, nullptr, QKVb, VT, nullptr, 2304, Cc, Cc, 2304);
    attn_k<<<dim3(Tc / 64, Bc * Hc), 256, 0, stream>>>(QKVb, VT, ATT);
    gemm_bt<4><<<dim3(6, 32, 2), 256, 0, stream>>>(ATT, wp, nullptr, nullptr, nullptr, FPROJ, Cc, Cc / 2, Cc, Cc);
    red_ln<<<BT / 4, 256, 0, stream>>>(FPROJ, bp + (size_t)l * Cc, ln2g + (size_t)l * Cc, ln2b + (size_t)l * Cc, X, Hb);
    gemm_bt<1><<<dim3(24, 32), 256, 0, stream>>>(Hb, w1, b1 + (size_t)l * FFc, FFb, nullptr, nullptr, FFc, Cc, Cc, FFc);
    gemm_bt<4><<<dim3(6, 32, 2), 256, 0, stream>>>(FFb, w2, nullptr, nullptr, nullptr, FPART, Cc, FFc / 2, FFc, Cc);
    const float* gN = (l + 1 < Lc) ? ln1g + (size_t)(l + 1) * Cc : lnfg;
    const float* bN = (l + 1 < Lc) ? ln1b + (size_t)(l + 1) * Cc : lnfb;
    red_ln<<<BT / 4, 256, 0, stream>>>(FPART, b2 + (size_t)l * Cc, gN, bN, X, Hb);
  }
  head_k<<<dim3(NPAN, 32), 256, 0, stream>>>(Hb, WTH, bh, (float*)d_out, Cc, Vc, PART1);
  loss_rows<<<BT / 4, 256, 0, stream>>>(PART1, (const float*)d_out, tgt, PART);
  loss_final<<<1, 256, 0, stream>>>(PART, (float*)d_out + (size_t)BT * Vc);
}

// Round 13
// 1659.292 us; speedup vs baseline: 1.0959x; 1.0959x over previous
//
#include <hip/hip_runtime.h>
#include <hip/hip_bf16.h>

#define DI __device__ __forceinline__

typedef __bf16 bf16_t;
typedef __bf16 bf16x8 __attribute__((ext_vector_type(8)));
typedef float f32x4 __attribute__((ext_vector_type(4)));

static constexpr int Bc = 4, Tc = 1024, Cc = 768, Hc = 12, Lc = 6, Vc = 50257;
static constexpr int FFc = 3072, BT = Bc * Tc;  // 4096
static constexpr int Vpad = 50304;              // 393 * 128
static constexpr int NPAN = Vpad / 128;         // 393 head panels

DI void gld_lds16(const void* g, void* l) {
  __builtin_amdgcn_global_load_lds((__attribute__((address_space(1))) void*)(void*)g,
                                   (__attribute__((address_space(3))) void*)l, 16, 0, 0);
}
DI bf16_t f2b(float v) { return (bf16_t)v; }
DI unsigned short b2u(bf16_t h) { union { bf16_t b; unsigned short u; } x; x.b = h; return x.u; }

// ---------------- weight transpose + f32->bf16 convert: src[K][N] -> dst[Npad][K]
__global__ void tconv(const float* __restrict__ src, bf16_t* __restrict__ dst,
                      const int K, const int N, const long sStride, const long dStride) {
  __shared__ float t[32][33];
  src += (long)blockIdx.z * sStride;
  dst += (long)blockIdx.z * dStride;
  const int n0 = blockIdx.x * 32, k0 = blockIdx.y * 32;
  const int tr = threadIdx.x >> 5, tc = threadIdx.x & 31;
#pragma unroll
  for (int i = 0; i < 4; ++i) {
    const int n = n0 + tc;
    t[tr + i * 8][tc] = (n < N) ? src[(long)(k0 + tr + i * 8) * N + n] : 0.f;
  }
  __syncthreads();
#pragma unroll
  for (int i = 0; i < 4; ++i)
    dst[(long)(n0 + tr + i * 8) * K + k0 + tc] = f2b(t[tc][tr + i * 8]);
}

// ---------------- fused embedding + LN1(layer 0): one wave per row, 4 rows/block
__global__ void embed_ln(const int* __restrict__ idx, const float* __restrict__ tok,
                         const float* __restrict__ pos, const float* __restrict__ g,
                         const float* __restrict__ b, float* __restrict__ X,
                         bf16_t* __restrict__ out) {
  const int lane = threadIdx.x & 63;
  const long row = (long)blockIdx.x * 4 + (threadIdx.x >> 6);
  const int t = (int)(row & (Tc - 1));
  const float* tr = tok + (long)idx[row] * Cc;
  const float* pr = pos + (long)t * Cc;
  float v[12];
  float s = 0.f;
#pragma unroll
  for (int i = 0; i < 3; ++i) {
    const int c = lane * 4 + i * 256;
    const float4 a = *(const float4*)(tr + c);
    const float4 p = *(const float4*)(pr + c);
    float4 x;
    x.x = a.x + p.x; x.y = a.y + p.y; x.z = a.z + p.z; x.w = a.w + p.w;
    *(float4*)(X + row * Cc + c) = x;
    v[i * 4 + 0] = x.x; v[i * 4 + 1] = x.y; v[i * 4 + 2] = x.z; v[i * 4 + 3] = x.w;
    s += x.x + x.y + x.z + x.w;
  }
#pragma unroll
  for (int o = 1; o < 64; o <<= 1) s += __shfl_xor(s, o);
  const float mean = s * (1.f / 768.f);
  float q = 0.f;
#pragma unroll
  for (int j = 0; j < 12; ++j) { const float d = v[j] - mean; q += d * d; }
#pragma unroll
  for (int o = 1; o < 64; o <<= 1) q += __shfl_xor(q, o);
  const float rstd = rsqrtf(q * (1.f / 768.f) + 1e-5f);
#pragma unroll
  for (int i = 0; i < 3; ++i) {
    const int c = lane * 4 + i * 256;
    const float4 gg = *(const float4*)(g + c);
    const float4 bb = *(const float4*)(b + c);
    ushort4 o4;
    o4.x = b2u(f2b((v[i * 4 + 0] - mean) * rstd * gg.x + bb.x));
    o4.y = b2u(f2b((v[i * 4 + 1] - mean) * rstd * gg.y + bb.y));
    o4.z = b2u(f2b((v[i * 4 + 2] - mean) * rstd * gg.z + bb.z));
    o4.w = b2u(f2b((v[i * 4 + 3] - mean) * rstd * gg.w + bb.w));
    *(ushort4*)(out + row * Cc + c) = o4;
  }
}

// ---------------- fused split-K reduce + residual + LN: X += P0+P1+bias; out = LN(X)
__global__ void red_ln(const float* __restrict__ P, const float* __restrict__ bias,
                       const float* __restrict__ g, const float* __restrict__ b,
                       float* __restrict__ X, bf16_t* __restrict__ out) {
  const int lane = threadIdx.x & 63;
  const long row = (long)blockIdx.x * 4 + (threadIdx.x >> 6);
  float v[12];
  float s = 0.f;
#pragma unroll
  for (int i = 0; i < 3; ++i) {
    const int c = lane * 4 + i * 256;
    const float4 x0 = *(const float4*)(X + row * Cc + c);
    const float4 p0 = *(const float4*)(P + row * Cc + c);
    const float4 p1 = *(const float4*)(P + (size_t)BT * Cc + row * Cc + c);
    const float4 bb = *(const float4*)(bias + c);
    float4 x;
    x.x = x0.x + p0.x + p1.x + bb.x;
    x.y = x0.y + p0.y + p1.y + bb.y;
    x.z = x0.z + p0.z + p1.z + bb.z;
    x.w = x0.w + p0.w + p1.w + bb.w;
    *(float4*)(X + row * Cc + c) = x;
    v[i * 4 + 0] = x.x; v[i * 4 + 1] = x.y; v[i * 4 + 2] = x.z; v[i * 4 + 3] = x.w;
    s += x.x + x.y + x.z + x.w;
  }
#pragma unroll
  for (int o = 1; o < 64; o <<= 1) s += __shfl_xor(s, o);
  const float mean = s * (1.f / 768.f);
  float q = 0.f;
#pragma unroll
  for (int j = 0; j < 12; ++j) { const float d = v[j] - mean; q += d * d; }
#pragma unroll
  for (int o = 1; o < 64; o <<= 1) q += __shfl_xor(q, o);
  const float rstd = rsqrtf(q * (1.f / 768.f) + 1e-5f);
#pragma unroll
  for (int i = 0; i < 3; ++i) {
    const int c = lane * 4 + i * 256;
    const float4 gg = *(const float4*)(g + c);
    const float4 bb = *(const float4*)(b + c);
    ushort4 o4;
    o4.x = b2u(f2b((v[i * 4 + 0] - mean) * rstd * gg.x + bb.x));
    o4.y = b2u(f2b((v[i * 4 + 1] - mean) * rstd * gg.y + bb.y));
    o4.z = b2u(f2b((v[i * 4 + 2] - mean) * rstd * gg.z + bb.z));
    o4.w = b2u(f2b((v[i * 4 + 3] - mean) * rstd * gg.w + bb.w));
    *(ushort4*)(out + row * Cc + c) = o4;
  }
}

// ---------------- 128x128 GEMM, m97 structure.
// EPI: 0 = bf16 out; 1 = bf16 relu(v+bias); 4 = split-K f32 partial (blockIdx.z);
//      5 = QKV: Q,K cols -> bf16 out; V cols (n0>=1536) -> transposed bf16 to vtr
template <int EPI>
__launch_bounds__(256, 4)
__global__ void gemm_bt(const bf16_t* __restrict__ A, const bf16_t* __restrict__ Bt,
                        const float* __restrict__ bias, bf16_t* __restrict__ outB,
                        bf16_t* __restrict__ vtr, float* __restrict__ fpart,
                        const int N, const int K, const int ldk, const int ldo) {
  __shared__ __align__(16) bf16_t As[128 * 64];
  __shared__ __align__(16) bf16_t Bs[128 * 64];
  const int tid = threadIdx.x;
  const int lane = tid & 63, wid = tid >> 6;
  const int l4 = lane >> 4, l15 = lane & 15;
  const int wr = wid >> 1, wc = wid & 1;

  int flat;
  {
    const int nwg = gridDim.x * gridDim.y;
    int f = (int)blockIdx.y * gridDim.x + (int)blockIdx.x;
    const int q = nwg >> 3, r = nwg & 7;
    const int xcd = f & 7, pos = f >> 3;
    flat = (xcd < r) ? xcd * (q + 1) + pos : r * (q + 1) + (xcd - r) * q + pos;
  }
  const long m0 = (long)(flat / gridDim.x) * 128;
  const long n0 = (long)(flat % gridDim.x) * 128;
  const long koff = (long)blockIdx.z * K;

  const bf16_t* Ag = A + m0 * ldk + koff;
  const bf16_t* Bg = Bt + n0 * ldk + koff;
  const int srow = tid >> 3, scol = tid & 7;

  f32x4 acc[4][4];
#pragma unroll
  for (int m = 0; m < 4; ++m)
#pragma unroll
    for (int n = 0; n < 4; ++n) acc[m][n] = (f32x4){0.f, 0.f, 0.f, 0.f};

  const int nkt = K >> 6;
  for (int kt = 0; kt < nkt; ++kt) {
    const int kb = kt << 6;
#pragma unroll
    for (int i = 0; i < 4; ++i) {
      const int r_ = i * 32 + srow;
      const int c8 = scol ^ (r_ & 7);
      gld_lds16(Ag + (long)r_ * ldk + kb + c8 * 8, As + (i * 256 + tid) * 8);
      gld_lds16(Bg + (long)r_ * ldk + kb + c8 * 8, Bs + (i * 256 + tid) * 8);
    }
    __syncthreads();
#pragma unroll
    for (int kk = 0; kk < 2; ++kk) {
      bf16x8 af[4], bfv[4];
#pragma unroll
      for (int m = 0; m < 4; ++m) {
        const int row = wr * 64 + m * 16 + l15;
        af[m] = *(const bf16x8*)((const char*)As +
                 ((row * 128 + kk * 64 + l4 * 16) ^ ((row & 7) << 4)));
      }
#pragma unroll
      for (int n = 0; n < 4; ++n) {
        const int row = wc * 64 + n * 16 + l15;
        bfv[n] = *(const bf16x8*)((const char*)Bs +
                 ((row * 128 + kk * 64 + l4 * 16) ^ ((row & 7) << 4)));
      }
#pragma unroll
      for (int m = 0; m < 4; ++m)
#pragma unroll
        for (int n = 0; n < 4; ++n)
          acc[m][n] = __builtin_amdgcn_mfma_f32_16x16x32_bf16(af[m], bfv[n], acc[m][n], 0, 0, 0);
    }
    __syncthreads();
  }

  if constexpr (EPI == 5) {
    if ((int)n0 >= 1536) {
      // V region: write ONLY transposed VT[(col-1536)][row], 8B per (m,n)
#pragma unroll
      for (int m = 0; m < 4; ++m) {
        const long rowb = m0 + wr * 64 + m * 16 + l4 * 4;
#pragma unroll
        for (int n = 0; n < 4; ++n) {
          const int col = (int)n0 + wc * 64 + n * 16 + l15;
          ushort4 w;
          w.x = b2u(f2b(acc[m][n][0]));
          w.y = b2u(f2b(acc[m][n][1]));
          w.z = b2u(f2b(acc[m][n][2]));
          w.w = b2u(f2b(acc[m][n][3]));
          *(ushort4*)(vtr + (size_t)(col - 1536) * BT + rowb) = w;
        }
      }
      return;
    }
  }
#pragma unroll
  for (int m = 0; m < 4; ++m) {
    const long rowb = m0 + wr * 64 + m * 16 + l4 * 4;
#pragma unroll
    for (int n = 0; n < 4; ++n) {
      const int col = (int)n0 + wc * 64 + n * 16 + l15;
#pragma unroll
      for (int r = 0; r < 4; ++r) {
        const float v = acc[m][n][r];
        const long row = rowb + r;
        if constexpr (EPI == 0 || EPI == 5) {
          outB[row * ldo + col] = f2b(v);
        } else if constexpr (EPI == 1) {
          const float z = v + bias[col];
          outB[row * ldo + col] = f2b(z > 0.f ? z : 0.f);
        } else {
          fpart[((size_t)blockIdx.z * BT + row) * ldo + col] = v;
        }
      }
    }
  }
}

// ---------------- HEAD: 128^2, n-fastest, occ-4. No-max partials, no shuffles.
// Plain (cached) logit stores — NT stores regressed (R12: WRITE_SIZE +50%).
__launch_bounds__(256, 4)
__global__ void head_k(const bf16_t* __restrict__ A, const bf16_t* __restrict__ Bt,
                       const float* __restrict__ bias, float* __restrict__ outF,
                       const int K, const int ldo, float* __restrict__ part1) {
  __shared__ __align__(16) bf16_t As[128 * 64];
  __shared__ __align__(16) bf16_t Bs[128 * 64];
  const int tid = threadIdx.x;
  const int lane = tid & 63, wid = tid >> 6;
  const int l4 = lane >> 4, l15 = lane & 15;
  const int wr = wid >> 1, wc = wid & 1;
  const long m0 = (long)blockIdx.y * 128;
  const long n0 = (long)blockIdx.x * 128;

  const bf16_t* Ag = A + m0 * K;
  const bf16_t* Bg = Bt + n0 * K;
  const int srow = tid >> 3, scol = tid & 7;

  f32x4 acc[4][4];
#pragma unroll
  for (int m = 0; m < 4; ++m)
#pragma unroll
    for (int n = 0; n < 4; ++n) acc[m][n] = (f32x4){0.f, 0.f, 0.f, 0.f};

  const int nkt = K >> 6;
  for (int kt = 0; kt < nkt; ++kt) {
    const int kb = kt << 6;
#pragma unroll
    for (int i = 0; i < 4; ++i) {
      const int r_ = i * 32 + srow;
      const int c8 = scol ^ (r_ & 7);
      gld_lds16(Ag + (long)r_ * K + kb + c8 * 8, As + (i * 256 + tid) * 8);
      gld_lds16(Bg + (long)r_ * K + kb + c8 * 8, Bs + (i * 256 + tid) * 8);
    }
    __syncthreads();
#pragma unroll
    for (int kk = 0; kk < 2; ++kk) {
      bf16x8 af[4], bfv[4];
#pragma unroll
      for (int m = 0; m < 4; ++m) {
        const int row = wr * 64 + m * 16 + l15;
        af[m] = *(const bf16x8*)((const char*)As +
                 ((row * 128 + kk * 64 + l4 * 16) ^ ((row & 7) << 4)));
      }
#pragma unroll
      for (int n = 0; n < 4; ++n) {
        const int row = wc * 64 + n * 16 + l15;
        bfv[n] = *(const bf16x8*)((const char*)Bs +
                 ((row * 128 + kk * 64 + l4 * 16) ^ ((row & 7) << 4)));
      }
#pragma unroll
      for (int m = 0; m < 4; ++m)
#pragma unroll
        for (int n = 0; n < 4; ++n)
          acc[m][n] = __builtin_amdgcn_mfma_f32_16x16x32_bf16(af[m], bfv[n], acc[m][n], 0, 0, 0);
    }
    __syncthreads();
  }

  const bool full = ((int)n0 + 128) <= Vc;  // 392/393 panels: no col guard needed

  // ---- thread-local exp-sums -> LDS transpose (no shuffles)
  float* ps = (float*)&As[0];  // [128][33]
#pragma unroll
  for (int m = 0; m < 4; ++m)
#pragma unroll
    for (int r = 0; r < 4; ++r) {
      float s = 0.f;
      if (full) {
#pragma unroll
        for (int n = 0; n < 4; ++n) {
          const int col = (int)n0 + wc * 64 + n * 16 + l15;
          s += __expf(acc[m][n][r] + bias[col]);
        }
      } else {
#pragma unroll
        for (int n = 0; n < 4; ++n) {
          const int col = (int)n0 + wc * 64 + n * 16 + l15;
          s += (col < Vc) ? __expf(acc[m][n][r] + bias[col]) : 0.f;
        }
      }
      ps[(wr * 64 + m * 16 + l4 * 4 + r) * 33 + wc * 16 + l15] = s;
    }
  __syncthreads();
  if (tid < 128) {
    float S = 0.f;
#pragma unroll
    for (int j = 0; j < 32; ++j) S += ps[tid * 33 + j];
    part1[(m0 + tid) * NPAN + (int)(n0 >> 7)] = S;
  }

  // ---- logit stores last (plain cached stores)
  if (full) {
#pragma unroll
    for (int m = 0; m < 4; ++m) {
      const long rowb = m0 + wr * 64 + m * 16 + l4 * 4;
#pragma unroll
      for (int n = 0; n < 4; ++n) {
        const int col = (int)n0 + wc * 64 + n * 16 + l15;
#pragma unroll
        for (int r = 0; r < 4; ++r)
          outF[(rowb + r) * (long)ldo + col] = acc[m][n][r] + bias[col];
      }
    }
  } else {
#pragma unroll
    for (int m = 0; m < 4; ++m) {
      const long rowb = m0 + wr * 64 + m * 16 + l4 * 4;
#pragma unroll
      for (int n = 0; n < 4; ++n) {
        const int col = (int)n0 + wc * 64 + n * 16 + l15;
#pragma unroll
        for (int r = 0; r < 4; ++r)
          if (col < Vc) outF[(rowb + r) * (long)ldo + col] = acc[m][n][r] + bias[col];
      }
    }
  }
}

// ---------------- causal flash attention. Grid (bh=48, qt=16): with all 768 blocks
// co-resident (3/CU), CU c's 3 blocks get qt ~ {c/48, c/48+5.3, c/48+10.7} (mixed)
// instead of 3x the SAME qt (old layout: makespan 48 units vs 33).
__launch_bounds__(256, 3)
__global__ void attn_k(const bf16_t* __restrict__ qkv, const bf16_t* __restrict__ vt,
                       bf16_t* __restrict__ att) {
  const int qt = blockIdx.y;
  const int bh = blockIdx.x;
  const int b = bh / Hc, h = bh % Hc;
  const int tid = threadIdx.x;
  const int lane = tid & 63, wid = tid >> 6;
  const int l4 = lane >> 4, l15 = lane & 15;

  __shared__ __align__(16) bf16_t Ks[64 * 64];    // swizzled [kv][64]
  __shared__ __align__(16) bf16_t Vts[64 * 64];   // swizzled [d][kv]
  __shared__ __align__(16) bf16_t Ps[4][16 * 64]; // per-wave swizzled P

  const long qrow0 = (long)b * Tc + qt * 64 + wid * 16;
  bf16x8 qf0, qf1;
  {
    const bf16_t* qp = qkv + (qrow0 + l15) * 2304 + h * 64 + l4 * 8;
    qf0 = *(const bf16x8*)qp;
    qf1 = *(const bf16x8*)(qp + 32);
  }
  f32x4 oacc[4];
#pragma unroll
  for (int f = 0; f < 4; ++f) oacc[f] = (f32x4){0.f, 0.f, 0.f, 0.f};
  float mrow[4] = {-3.0e38f, -3.0e38f, -3.0e38f, -3.0e38f};
  float lrw[4] = {0.f, 0.f, 0.f, 0.f};

  for (int kt = 0; kt <= qt; ++kt) {
    const long kvb = (long)b * Tc + kt * 64;
#pragma unroll
    for (int i = 0; i < 2; ++i) {  // K tile
      const int c = i * 256 + tid;
      const int r_ = c >> 3;
      const int c8 = (c & 7) ^ (r_ & 7);
      gld_lds16(qkv + (kvb + r_) * 2304 + Cc + h * 64 + c8 * 8, Ks + (size_t)c * 8);
    }
#pragma unroll
    for (int i = 0; i < 2; ++i) {  // V^T tile from global VT
      const int c = i * 256 + tid;
      const int r_ = c >> 3;
      const int c8 = (c & 7) ^ (r_ & 7);
      gld_lds16(vt + (size_t)(h * 64 + r_) * BT + kvb + c8 * 8, Vts + (size_t)c * 8);
    }
    __syncthreads();

    f32x4 sf[4];
#pragma unroll
    for (int f = 0; f < 4; ++f) {
      const int row = f * 16 + l15;
      const bf16x8 kb0 = *(const bf16x8*)((const char*)Ks +
                        ((row * 128 + l4 * 16) ^ ((row & 7) << 4)));
      const bf16x8 kb1 = *(const bf16x8*)((const char*)Ks +
                        ((row * 128 + 64 + l4 * 16) ^ ((row & 7) << 4)));
      f32x4 z = (f32x4){0.f, 0.f, 0.f, 0.f};
      z = __builtin_amdgcn_mfma_f32_16x16x32_bf16(qf0, kb0, z, 0, 0, 0);
      sf[f] = __builtin_amdgcn_mfma_f32_16x16x32_bf16(qf1, kb1, z, 0, 0, 0);
    }
    float alpha[4];
#pragma unroll
    for (int r = 0; r < 4; ++r) {
      const int qpos = qt * 64 + wid * 16 + l4 * 4 + r;
      float mx = -3.0e38f;
#pragma unroll
      for (int f = 0; f < 4; ++f) {
        const int kpos = kt * 64 + f * 16 + l15;
        float sv = sf[f][r] * 0.125f;
        sv = (kpos <= qpos) ? sv : -1e9f;
        sf[f][r] = sv;
        mx = fmaxf(mx, sv);
      }
      mx = fmaxf(mx, __shfl_xor(mx, 1));
      mx = fmaxf(mx, __shfl_xor(mx, 2));
      mx = fmaxf(mx, __shfl_xor(mx, 4));
      mx = fmaxf(mx, __shfl_xor(mx, 8));
      const float mn = fmaxf(mrow[r], mx);
      alpha[r] = __expf(mrow[r] - mn);
      mrow[r] = mn;
      float rs = 0.f;
#pragma unroll
      for (int f = 0; f < 4; ++f) {
        const float pw = __expf(sf[f][r] - mn);
        sf[f][r] = pw;
        rs += pw;
      }
      rs += __shfl_xor(rs, 1); rs += __shfl_xor(rs, 2);
      rs += __shfl_xor(rs, 4); rs += __shfl_xor(rs, 8);
      lrw[r] = lrw[r] * alpha[r] + rs;
    }
    char* pb = (char*)&Ps[wid][0];
#pragma unroll
    for (int r = 0; r < 4; ++r) {
      const int i_ = l4 * 4 + r;
#pragma unroll
      for (int f = 0; f < 4; ++f) {
        const int j_ = f * 16 + l15;
        *(bf16_t*)(pb + ((i_ * 128 + j_ * 2) ^ ((i_ & 7) << 4))) = f2b(sf[f][r]);
      }
    }
#pragma unroll
    for (int f = 0; f < 4; ++f)
#pragma unroll
      for (int r = 0; r < 4; ++r) oacc[f][r] *= alpha[r];

    bf16x8 pa0, pa1;
    {
      const int row = l15;
      pa0 = *(const bf16x8*)(pb + ((row * 128 + l4 * 16) ^ ((row & 7) << 4)));
      pa1 = *(const bf16x8*)(pb + ((row * 128 + 64 + l4 * 16) ^ ((row & 7) << 4)));
    }
#pragma unroll
    for (int f = 0; f < 4; ++f) {
      const int row = f * 16 + l15;
      const bf16x8 vb0 = *(const bf16x8*)((const char*)Vts +
                        ((row * 128 + l4 * 16) ^ ((row & 7) << 4)));
      const bf16x8 vb1 = *(const bf16x8*)((const char*)Vts +
                        ((row * 128 + 64 + l4 * 16) ^ ((row & 7) << 4)));
      oacc[f] = __builtin_amdgcn_mfma_f32_16x16x32_bf16(pa0, vb0, oacc[f], 0, 0, 0);
      oacc[f] = __builtin_amdgcn_mfma_f32_16x16x32_bf16(pa1, vb1, oacc[f], 0, 0, 0);
    }
    __syncthreads();
  }
#pragma unroll
  for (int f = 0; f < 4; ++f) {
    const int col = h * 64 + f * 16 + l15;
#pragma unroll
    for (int r = 0; r < 4; ++r) {
      const long row = qrow0 + l4 * 4 + r;
      att[row * Cc + col] = f2b(oacc[f][r] / lrw[r]);
    }
  }
}

// ---------------- loss
__global__ void loss_rows(const float* __restrict__ p1, const float* __restrict__ logits,
                          const int* __restrict__ tgt, float* __restrict__ part) {
  const int row = blockIdx.x * 4 + (threadIdx.x >> 6);
  const int lane = threadIdx.x & 63;
  float S = 0.f;
  for (int i = lane; i < NPAN; i += 64) S += p1[(long)row * NPAN + i];
#pragma unroll
  for (int o = 1; o < 64; o <<= 1) S += __shfl_xor(S, o);
  if (lane == 0)
    part[row] = logf(S) - logits[(long)row * Vc + tgt[row]];
}

__global__ void loss_final(const float* __restrict__ part, float* __restrict__ out) {
  float s = 0.f;
  for (int i = threadIdx.x; i < BT; i += 256) s += part[i];
#pragma unroll
  for (int o = 1; o < 64; o <<= 1) s += __shfl_xor(s, o);
  __shared__ float sw[4];
  const int wid = threadIdx.x >> 6;
  if ((threadIdx.x & 63) == 0) sw[wid] = s;
  __syncthreads();
  if (threadIdx.x == 0) out[0] = (sw[0] + sw[1] + sw[2] + sw[3]) / (float)BT;
}

extern "C" void kernel_launch(void* const* d_in, const int* in_sizes, int n_in,
                              void* d_out, int out_size, void* d_ws, size_t ws_size,
                              hipStream_t stream) {
  (void)in_sizes; (void)n_in; (void)out_size; (void)ws_size;
  const int* idx = (const int*)d_in[0];
  const int* tgt = (const int*)d_in[1];
  const float* tok = (const float*)d_in[2];
  const float* pos = (const float*)d_in[3];
  const float* Wq = (const float*)d_in[4];
  const float* Wk = (const float*)d_in[5];
  const float* Wv = (const float*)d_in[6];
  const float* Wp = (const float*)d_in[7];
  const float* bp = (const float*)d_in[8];
  const float* ln1g = (const float*)d_in[9];
  const float* ln1b = (const float*)d_in[10];
  const float* ln2g = (const float*)d_in[11];
  const float* ln2b = (const float*)d_in[12];
  const float* W1 = (const float*)d_in[13];
  const float* b1 = (const float*)d_in[14];
  const float* W2 = (const float*)d_in[15];
  const float* b2 = (const float*)d_in[16];
  const float* lnfg = (const float*)d_in[17];
  const float* lnfb = (const float*)d_in[18];
  const float* Wh = (const float*)d_in[19];
  const float* bh = (const float*)d_in[20];

  char* p = (char*)d_ws;
  auto take = [&](size_t bytes) { char* r = p; p += (bytes + 255) & ~(size_t)255; return r; };
  bf16_t* WTQKV = (bf16_t*)take((size_t)Lc * 2304 * Cc * 2);
  bf16_t* WTP   = (bf16_t*)take((size_t)Lc * Cc * Cc * 2);
  bf16_t* WT1   = (bf16_t*)take((size_t)Lc * FFc * Cc * 2);
  bf16_t* WT2   = (bf16_t*)take((size_t)Lc * Cc * FFc * 2);
  bf16_t* WTH   = (bf16_t*)take((size_t)Vpad * Cc * 2);
  float*  X     = (float*)take((size_t)BT * Cc * 4);
  bf16_t* Hb    = (bf16_t*)take((size_t)BT * Cc * 2);
  bf16_t* QKVb  = (bf16_t*)take((size_t)BT * 2304 * 2);
  bf16_t* ATT   = (bf16_t*)take((size_t)BT * Cc * 2);
  bf16_t* FFb   = (bf16_t*)take((size_t)BT * FFc * 2);
  bf16_t* VT    = (bf16_t*)take((size_t)BT * Cc * 2);      // V transposed [768][BT]
  float*  FPROJ = (float*)take((size_t)2 * BT * Cc * 4);   // proj split-K partials
  float*  FPART = (float*)QKVb;   // FF2 partials: QKVb+ATT dead during FF2
  float*  PART1 = (float*)FFb;    // head exp-sums (FFb dead after last FF2)
  float*  PART  = (float*)ATT;    // 16 KB row losses

  tconv<<<dim3(24, 24, Lc), 256, 0, stream>>>(Wq, WTQKV, Cc, Cc, (long)Cc * Cc, (long)2304 * Cc);
  tconv<<<dim3(24, 24, Lc), 256, 0, stream>>>(Wk, WTQKV + (size_t)Cc * Cc, Cc, Cc, (long)Cc * Cc, (long)2304 * Cc);
  tconv<<<dim3(24, 24, Lc), 256, 0, stream>>>(Wv, WTQKV + (size_t)2 * Cc * Cc, Cc, Cc, (long)Cc * Cc, (long)2304 * Cc);
  tconv<<<dim3(24, 24, Lc), 256, 0, stream>>>(Wp, WTP, Cc, Cc, (long)Cc * Cc, (long)Cc * Cc);
  tconv<<<dim3(96, 24, Lc), 256, 0, stream>>>(W1, WT1, Cc, FFc, (long)Cc * FFc, (long)FFc * Cc);
  tconv<<<dim3(24, 96, Lc), 256, 0, stream>>>(W2, WT2, FFc, Cc, (long)FFc * Cc, (long)Cc * FFc);
  tconv<<<dim3(Vpad / 32, 24, 1), 256, 0, stream>>>(Wh, WTH, Cc, Vc, 0, 0);

  embed_ln<<<BT / 4, 256, 0, stream>>>(idx, tok, pos, ln1g, ln1b, X, Hb);

  for (int l = 0; l < Lc; ++l) {
    const bf16_t* wqkv = WTQKV + (size_t)l * 2304 * Cc;
    const bf16_t* wp   = WTP + (size_t)l * Cc * Cc;
    const bf16_t* w1   = WT1 + (size_t)l * FFc * Cc;
    const bf16_t* w2   = WT2 + (size_t)l * Cc * FFc;
    gemm_bt<5><<<dim3(18, 32), 256, 0, stream>>>(Hb, wqkv, nullptr, QKVb, VT, nullptr, 2304, Cc, Cc, 2304);
    attn_k<<<dim3(Bc * Hc, Tc / 64), 256, 0, stream>>>(QKVb, VT, ATT);
    gemm_bt<4><<<dim3(6, 32, 2), 256, 0, stream>>>(ATT, wp, nullptr, nullptr, nullptr, FPROJ, Cc, Cc / 2, Cc, Cc);
    red_ln<<<BT / 4, 256, 0, stream>>>(FPROJ, bp + (size_t)l * Cc, ln2g + (size_t)l * Cc, ln2b + (size_t)l * Cc, X, Hb);
    gemm_bt<1><<<dim3(24, 32), 256, 0, stream>>>(Hb, w1, b1 + (size_t)l * FFc, FFb, nullptr, nullptr, FFc, Cc, Cc, FFc);
    gemm_bt<4><<<dim3(6, 32, 2), 256, 0, stream>>>(FFb, w2, nullptr, nullptr, nullptr, FPART, Cc, FFc / 2, FFc, Cc);
    const float* gN = (l + 1 < Lc) ? ln1g + (size_t)(l + 1) * Cc : lnfg;
    const float* bN = (l + 1 < Lc) ? ln1b + (size_t)(l + 1) * Cc : lnfb;
    red_ln<<<BT / 4, 256, 0, stream>>>(FPART, b2 + (size_t)l * Cc, gN, bN, X, Hb);
  }
  head_k<<<dim3(NPAN, 32), 256, 0, stream>>>(Hb, WTH, bh, (float*)d_out, Cc, Vc, PART1);
  loss_rows<<<BT / 4, 256, 0, stream>>>(PART1, (const float*)d_out, tgt, PART);
  loss_final<<<1, 256, 0, stream>>>(PART, (float*)d_out + (size_t)BT * Vc);
}